// Round 11
// baseline (143.607 us; speedup 1.0000x reference)
//
#include <hip/hip_runtime.h>
#include <hip/hip_bf16.h>

typedef __attribute__((ext_vector_type(8))) short bf16x8;
typedef __attribute__((ext_vector_type(4))) short bf16x4;
typedef __attribute__((ext_vector_type(4))) float f32x4;

constexpr int NT   = 512;   // tiles
constexpr int NP   = 512;   // points (M)
constexpr int DIN  = 256;   // K
constexpr int DOUT = 256;   // N

__device__ __forceinline__ short f2bf(float f) {
  __hip_bfloat16 h = __float2bfloat16(f);
  return __builtin_bit_cast(short, h);
}

// Workgroup barrier WITHOUT the vmcnt(0) drain __syncthreads() implies.
__device__ __forceinline__ void wg_barrier() {
  asm volatile("s_waitcnt lgkmcnt(0)" ::: "memory");
  __builtin_amdgcn_s_barrier();
  __builtin_amdgcn_sched_barrier(0);
}

// Ws: [n=256][k=256] bf16, 128 KB. Granule = 8 elem (16 B).
__device__ __forceinline__ int wsw(int n, int k) {
  return n * DIN + (k ^ (((n ^ (n >> 2)) & 7) << 3));
}

// Xs: [m=128][k=64] bf16, 16 KB per buffer.
__device__ __forceinline__ int xsw(int m, int k) {
  return m * 64 + (k ^ ((m & 7) << 3));
}

__global__ __launch_bounds__(1024, 4) void adaptive_linear_v6(
    const float* __restrict__ x,     // [NT][NP][DIN]
    const int*   __restrict__ idx,   // [NT]
    const float* __restrict__ w,     // [CH][DIN][DOUT]
    const float* __restrict__ bias,  // [DOUT]
    float*       __restrict__ out)   // [NT][NP][DOUT]
{
  __shared__ short Ws[DOUT * DIN];     // 128 KB
  __shared__ short Xs[2][128 * 64];    // 2 x 16 KB  (160 KiB total)

  const int tid = threadIdx.x;
  const int t   = blockIdx.x;

  const int c = idx[t];
  const float* xb = x   + (size_t)t * NP * DIN;
  const float* wb = w   + (size_t)c * DIN * DOUT;
  float*       ob = out + (size_t)t * NP * DOUT;

  // ---- staging decompositions (1024 threads) ---------------------------
  const int wl = tid & 63;             // W: n4 = wl*4 ; one 1 KB row per instr
  const int wv = tid >> 6;             // W: k-subgroup 0..15 (4 rows each/slab)
  const int xrow = tid >> 3;           // x: 0..127
  const int xo   = (tid & 7) * 8;      // x: k-offset (8 floats per thread)

  f32x4 wr[4];                         // W stage regs (4 rows)
  f32x4 xr[2][2];                      // x stage regs (double buffer)

  auto load_w = [&](int ss) {
    const float* ws = wb + (size_t)(ss * 64 + wv * 4) * DOUT + wl * 4;
    #pragma unroll
    for (int q = 0; q < 4; ++q)
      wr[q] = *reinterpret_cast<const f32x4*>(ws + (size_t)q * DOUT);
  };
  auto write_w = [&](int ss) {         // cvt + transposed LDS write
    const int k0 = ss * 64 + wv * 4;
    #pragma unroll
    for (int j = 0; j < 4; ++j) {
      bf16x4 v = { f2bf(wr[0][j]), f2bf(wr[1][j]),
                   f2bf(wr[2][j]), f2bf(wr[3][j]) };
      *reinterpret_cast<bf16x4*>(&Ws[wsw(wl * 4 + j, k0)]) = v;
    }
  };
  auto load_x = [&](int s, int p) {    // issue globals for step s into xr[p]
    const int cc = s >> 2, kk = s & 3;
    const float* xs = xb + (size_t)(cc * 128 + xrow) * DIN + kk * 64 + xo;
    xr[p][0] = *reinterpret_cast<const f32x4*>(xs);
    xr[p][1] = *reinterpret_cast<const f32x4*>(xs + 4);
  };
  auto write_x = [&](int p, int b) {   // cvt + single b128 LDS write
    bf16x8 v;
    #pragma unroll
    for (int i = 0; i < 2; ++i)
      #pragma unroll
      for (int j = 0; j < 4; ++j)
        v[i * 4 + j] = f2bf(xr[p][i][j]);
    *reinterpret_cast<bf16x8*>(&Xs[b][xsw(xrow, xo)]) = v;
  };

  // ---- wave decomposition: 4 (M) x 4 (N); wave owns 32 x 64 ------------
  const int l    = tid & 63;
  const int wid  = tid >> 6;           // 0..15
  const int wm   = wid >> 2;           // 0..3
  const int wn   = wid & 3;            // 0..3
  const int lrow = l & 15;
  const int lk   = l >> 4;             // 0..3

  float bv[4];
  #pragma unroll
  for (int fn = 0; fn < 4; ++fn)
    bv[fn] = bias[wn * 64 + fn * 16 + lrow];

  // ---- prologue --------------------------------------------------------
  load_w(0);
  load_x(0, 0);
  write_w(0);
  write_x(0, 0);         // Xs[0] <- x(0)
  load_w(1);
  load_x(1, 1);          // xr[1] <- x(1), stays in flight across the barrier
  wg_barrier();

  f32x4 acc[2][4] = {};

  for (int c4 = 0; c4 < 4; ++c4) {       // M-chunks of 128 rows
    #pragma unroll
    for (int ks = 0; ks < 4; ++ks) {     // K-steps of 64; s = c4*4+ks
      const int s = c4 * 4 + ks;

      // 1. issue x loads for step s+2
      if (s < 14) load_x(s + 2, ks & 1);

      // 2. publish x(s+1) into the other LDS buffer
      if (s < 15) write_x((ks + 1) & 1, (ks + 1) & 1);

      // 3. W pipeline, chunk 0 only
      if (c4 == 0 && ks < 3) {
        write_w(ks + 1);
        if (ks < 2) load_w(ks + 2);
      }

      // 4. compute from Xs[ks&1] and Ws k-range ks*64
      #pragma unroll
      for (int kc = 0; kc < 2; ++kc) {
        const int kb = kc * 32 + lk * 8;
        bf16x8 a[2], b[4];
        #pragma unroll
        for (int fm = 0; fm < 2; ++fm)
          a[fm] = *reinterpret_cast<const bf16x8*>(
              &Xs[ks & 1][xsw(wm * 32 + fm * 16 + lrow, kb)]);
        #pragma unroll
        for (int fn = 0; fn < 4; ++fn)
          b[fn] = *reinterpret_cast<const bf16x8*>(
              &Ws[wsw(wn * 64 + fn * 16 + lrow, ks * 64 + kb)]);
        #pragma unroll
        for (int fm = 0; fm < 2; ++fm)
          #pragma unroll
          for (int fn = 0; fn < 4; ++fn)
            acc[fm][fn] = __builtin_amdgcn_mfma_f32_16x16x32_bf16(
                a[fm], b[fn], acc[fm][fn], 0, 0, 0);
      }

      // 5. per-chunk epilogue: add bias, plain f32 stores
      if (ks == 3) {
        #pragma unroll
        for (int fm = 0; fm < 2; ++fm) {
          const int r0w = c4 * 128 + wm * 32 + fm * 16 + lk * 4;
          #pragma unroll
          for (int fn = 0; fn < 4; ++fn) {
            const int col = wn * 64 + fn * 16 + lrow;
            float* op = ob + (size_t)r0w * DOUT + col;
            #pragma unroll
            for (int rr = 0; rr < 4; ++rr)
              op[(size_t)rr * DOUT] = acc[fm][fn][rr] + bv[fn];
          }
        }
        #pragma unroll
        for (int fm = 0; fm < 2; ++fm)
          #pragma unroll
          for (int fn = 0; fn < 4; ++fn)
            acc[fm][fn] = f32x4{0.f, 0.f, 0.f, 0.f};
      }

      if (s < 15) wg_barrier();          // lgkm-only barrier
    }
  }
}

extern "C" void kernel_launch(void* const* d_in, const int* in_sizes, int n_in,
                              void* d_out, int out_size, void* d_ws, size_t ws_size,
                              hipStream_t stream) {
  const float* x    = (const float*)d_in[0];
  const int*   idx  = (const int*)d_in[1];
  const float* w    = (const float*)d_in[2];
  const float* bias = (const float*)d_in[3];
  float* out = (float*)d_out;

  adaptive_linear_v6<<<NT, 1024, 0, stream>>>(x, idx, w, bias, out);
}

// Round 13
// 135.045 us; speedup vs baseline: 1.0634x; 1.0634x over previous
//
#include <hip/hip_runtime.h>
#include <hip/hip_bf16.h>

typedef __attribute__((ext_vector_type(8))) short bf16x8;
typedef __attribute__((ext_vector_type(4))) short bf16x4;
typedef __attribute__((ext_vector_type(4))) float f32x4;

constexpr int NT   = 512;   // tiles
constexpr int NP   = 512;   // points (M)
constexpr int DIN  = 256;   // K
constexpr int DOUT = 256;   // N
constexpr int CHM  = 64;    // M-chunk rows

__device__ __forceinline__ short f2bf(float f) {
  __hip_bfloat16 h = __float2bfloat16(f);
  return __builtin_bit_cast(short, h);
}

// Workgroup barrier WITHOUT the vmcnt(0) drain __syncthreads() implies.
__device__ __forceinline__ void wg_barrier() {
  asm volatile("s_waitcnt lgkmcnt(0)" ::: "memory");
  __builtin_amdgcn_s_barrier();
  __builtin_amdgcn_sched_barrier(0);
}

// Ws: [n=256][k=256] bf16, 128 KB. Granule = 8 elem (16 B).
__device__ __forceinline__ int wsw(int n, int k) {
  return n * DIN + (k ^ (((n ^ (n >> 2)) & 7) << 3));
}

// Xs: [m=64][k=256] bf16, 32 KB. Row-XOR of the 16 B granule.
__device__ __forceinline__ int xsw(int m, int k) {
  return m * DIN + (k ^ ((m & 7) << 3));
}

__global__ __launch_bounds__(512, 2) void adaptive_linear_v7(
    const float* __restrict__ x,     // [NT][NP][DIN]
    const int*   __restrict__ idx,   // [NT]
    const float* __restrict__ w,     // [CH][DIN][DOUT]
    const float* __restrict__ bias,  // [DOUT]
    float*       __restrict__ out)   // [NT][NP][DOUT]
{
  __shared__ short Ws[DOUT * DIN];   // 128 KB
  __shared__ short Xs[CHM * DIN];    // 32 KB  (160 KiB total)

  const int tid = threadIdx.x;
  const int t   = blockIdx.x;

  const int c = idx[t];
  const float* xb = x   + (size_t)t * NP * DIN;
  const float* wb = w   + (size_t)c * DIN * DOUT;
  float*       ob = out + (size_t)t * NP * DOUT;

  // ---- W staging (v5-proven): wave wv streams 8 k-rows, 1 KB/instr ------
  const int wl = tid & 63;
  const int wv = tid >> 6;
  f32x4 wr[8];

  auto load_w = [&](int ss) {
    const float* ws = wb + (size_t)(ss * 64 + wv * 8) * DOUT + wl * 4;
    #pragma unroll
    for (int q = 0; q < 8; ++q)
      wr[q] = *reinterpret_cast<const f32x4*>(ws + (size_t)q * DOUT);
  };
  auto write_w = [&](int ss) {
    #pragma unroll
    for (int h = 0; h < 2; ++h) {
      const int k0 = ss * 64 + wv * 8 + h * 4;
      #pragma unroll
      for (int j = 0; j < 4; ++j) {
        bf16x4 v = { f2bf(wr[h*4+0][j]), f2bf(wr[h*4+1][j]),
                     f2bf(wr[h*4+2][j]), f2bf(wr[h*4+3][j]) };
        *reinterpret_cast<bf16x4*>(&Ws[wsw(wl * 4 + j, k0)]) = v;
      }
    }
  };

  // ---- x staging: whole 64x256 chunk; instr i reads 8 KB contiguous -----
  // f32 index f = tid*4 + i*2048 -> m = (tid>>6)+i*8, k = (tid&63)*4
  f32x4 xr[8];
  auto load_x = [&](int ch) {
    const float* base = xb + (size_t)ch * CHM * DIN;
    #pragma unroll
    for (int i = 0; i < 8; ++i)
      xr[i] = *reinterpret_cast<const f32x4*>(base + i * 2048 + tid * 4);
  };
  auto write_x = [&]() {
    const int m0 = tid >> 6;
    const int k  = (tid & 63) * 4;
    #pragma unroll
    for (int i = 0; i < 8; ++i) {
      bf16x4 v = { f2bf(xr[i][0]), f2bf(xr[i][1]),
                   f2bf(xr[i][2]), f2bf(xr[i][3]) };
      *reinterpret_cast<bf16x4*>(&Xs[xsw(m0 + i * 8, k)]) = v;
    }
  };

  // ---- wave decomposition: 2 (M) x 4 (N); wave owns 32 x 64 -------------
  const int l    = tid & 63;
  const int wid  = tid >> 6;
  const int wm   = wid >> 2;         // 0..1
  const int wn   = wid & 3;          // 0..3
  const int lrow = l & 15;
  const int lk   = l >> 4;           // 0..3

  float bv[4];
  #pragma unroll
  for (int fn = 0; fn < 4; ++fn)
    bv[fn] = bias[wn * 64 + fn * 16 + lrow];

  // ---- prologue: x chunk 0 in flight under the W slab pipeline ----------
  load_x(0);
  load_w(0);
  write_w(0);
  load_w(1); write_w(1);
  load_w(2); write_w(2);
  load_w(3); write_w(3);
  write_x();               // x loads long since landed
  wg_barrier();

  for (int ch = 0; ch < 8; ++ch) {
    // 1. issue next chunk's x loads — a full epoch of latency budget
    if (ch < 7) load_x(ch + 1);

    // 2. full-K compute for this 64-row chunk
    f32x4 acc[2][4] = {};
    #pragma unroll
    for (int ks = 0; ks < 8; ++ks) {   // 8 k-slices of 32
      const int kb = ks * 32 + lk * 8;
      bf16x8 a[2], b[4];
      #pragma unroll
      for (int fm = 0; fm < 2; ++fm)
        a[fm] = *reinterpret_cast<const bf16x8*>(
            &Xs[xsw(wm * 32 + fm * 16 + lrow, kb)]);
      #pragma unroll
      for (int fn = 0; fn < 4; ++fn)
        b[fn] = *reinterpret_cast<const bf16x8*>(
            &Ws[wsw(wn * 64 + fn * 16 + lrow, kb)]);
      #pragma unroll
      for (int fm = 0; fm < 2; ++fm)
        #pragma unroll
        for (int fn = 0; fn < 4; ++fn)
          acc[fm][fn] = __builtin_amdgcn_mfma_f32_16x16x32_bf16(
              a[fm], b[fn], acc[fm][fn], 0, 0, 0);
    }

    // 3. epilogue: add bias, plain f32 stores (stay async)
    #pragma unroll
    for (int fm = 0; fm < 2; ++fm) {
      const int r0w = ch * CHM + wm * 32 + fm * 16 + lk * 4;
      #pragma unroll
      for (int fn = 0; fn < 4; ++fn) {
        const int col = wn * 64 + fn * 16 + lrow;
        float* op = ob + (size_t)r0w * DOUT + col;
        #pragma unroll
        for (int rr = 0; rr < 4; ++rr)
          op[(size_t)rr * DOUT] = acc[fm][fn][rr] + bv[fn];
      }
    }

    // 4. publish next chunk into Xs
    if (ch < 7) {
      wg_barrier();        // all waves done reading Xs
      write_x();           // counted vmcnt waits only on xr regs
      wg_barrier();        // Xs(ch+1) visible
    }
  }
}

extern "C" void kernel_launch(void* const* d_in, const int* in_sizes, int n_in,
                              void* d_out, int out_size, void* d_ws, size_t ws_size,
                              hipStream_t stream) {
  const float* x    = (const float*)d_in[0];
  const int*   idx  = (const int*)d_in[1];
  const float* w    = (const float*)d_in[2];
  const float* bias = (const float*)d_in[3];
  float* out = (float*)d_out;

  adaptive_linear_v7<<<NT, 512, 0, stream>>>(x, idx, w, bias, out);
}

// Round 16
// 131.901 us; speedup vs baseline: 1.0887x; 1.0238x over previous
//
#include <hip/hip_runtime.h>
#include <hip/hip_bf16.h>

typedef __attribute__((ext_vector_type(8))) short bf16x8;
typedef __attribute__((ext_vector_type(4))) short bf16x4;
typedef __attribute__((ext_vector_type(4))) float f32x4;

constexpr int NT   = 512;   // tiles
constexpr int NP   = 512;   // points (M)
constexpr int DIN  = 256;   // K
constexpr int DOUT = 256;   // N
constexpr int CHM  = 32;    // M-chunk rows per epoch
constexpr int NEP  = NP / CHM;  // 16 epochs

__device__ __forceinline__ short f2bf(float f) {
  __hip_bfloat16 h = __float2bfloat16(f);
  return __builtin_bit_cast(short, h);
}

// Workgroup barrier WITHOUT the vmcnt(0) drain __syncthreads() implies.
__device__ __forceinline__ void wg_barrier() {
  asm volatile("s_waitcnt lgkmcnt(0)" ::: "memory");
  __builtin_amdgcn_s_barrier();
  __builtin_amdgcn_sched_barrier(0);
}

// Ws: [n=256][k=256] bf16, 128 KB. Granule = 8 elem (16 B).
__device__ __forceinline__ int wsw(int n, int k) {
  return n * DIN + (k ^ (((n ^ (n >> 2)) & 7) << 3));
}

// Xs chunk: [m=32][k=256] bf16, 16 KB per buffer.
__device__ __forceinline__ int xsw(int m, int k) {
  return m * DIN + (k ^ ((m & 7) << 3));
}

__global__ __launch_bounds__(512, 2) void adaptive_linear_v8(
    const float* __restrict__ x,     // [NT][NP][DIN]
    const int*   __restrict__ idx,   // [NT]
    const float* __restrict__ w,     // [CH][DIN][DOUT]
    const float* __restrict__ bias,  // [DOUT]
    float*       __restrict__ out)   // [NT][NP][DOUT]
{
  __shared__ short Ws[DOUT * DIN];      // 128 KB
  __shared__ short Xs[2][CHM * DIN];    // 2 x 16 KB  (160 KiB total)

  const int tid = threadIdx.x;
  const int t   = blockIdx.x;

  const int c = idx[t];
  const float* xb = x   + (size_t)t * NP * DIN;
  const float* wb = w   + (size_t)c * DIN * DOUT;
  float*       ob = out + (size_t)t * NP * DOUT;

  const int l   = tid & 63;
  const int wid = tid >> 6;            // 0..7

  // ---- W staging (all 8 waves, prologue only) ---------------------------
  const int wl = tid & 63;
  const int wv = tid >> 6;
  f32x4 wr[8];
  auto load_w = [&](int ss) {
    const float* ws = wb + (size_t)(ss * 64 + wv * 8) * DOUT + wl * 4;
    #pragma unroll
    for (int q = 0; q < 8; ++q)
      wr[q] = *reinterpret_cast<const f32x4*>(ws + (size_t)q * DOUT);
  };
  auto write_w = [&](int ss) {
    #pragma unroll
    for (int h = 0; h < 2; ++h) {
      const int k0 = ss * 64 + wv * 8 + h * 4;
      #pragma unroll
      for (int j = 0; j < 4; ++j) {
        bf16x4 v = { f2bf(wr[h*4+0][j]), f2bf(wr[h*4+1][j]),
                     f2bf(wr[h*4+2][j]), f2bf(wr[h*4+3][j]) };
        *reinterpret_cast<bf16x4*>(&Ws[wsw(wl * 4 + j, k0)]) = v;
      }
    }
  };

  // ---- roles ------------------------------------------------------------
  const bool producer = (wid < 4);
  const int  p = wid;                  // producer index 0..3 (rows p*8..p*8+7)
  const int  q = wid - 4;              // consumer index 0..3 (n-slice q*64)

  // producer state: one x row (1 KB) per load instr
  f32x4 xr[8];
  auto load_x = [&](int ch) {          // issue chunk ch's 8 row-loads
    const float* base = xb + (size_t)ch * CHM * DIN + (size_t)(p * 8) * DIN + l * 4;
    #pragma unroll
    for (int i = 0; i < 8; ++i)
      xr[i] = *reinterpret_cast<const f32x4*>(base + (size_t)i * DIN);
  };
  auto write_x = [&](int b) {          // cvt + one 512 B ds_write row each
    #pragma unroll
    for (int i = 0; i < 8; ++i) {
      bf16x4 v = { f2bf(xr[i][0]), f2bf(xr[i][1]),
                   f2bf(xr[i][2]), f2bf(xr[i][3]) };
      *reinterpret_cast<bf16x4*>(&Xs[b][xsw(p * 8 + i, l * 4)]) = v;
    }
  };

  // consumer state
  const int lrow = l & 15;
  const int lk   = l >> 4;             // 0..3
  float bv[4];
  if (!producer) {
    #pragma unroll
    for (int fn = 0; fn < 4; ++fn)
      bv[fn] = bias[q * 64 + fn * 16 + lrow];
  }

  // ---- prologue ---------------------------------------------------------
  if (producer) load_x(0);             // x(0) issued first, lands under W stage
  load_w(0); write_w(0);
  load_w(1); write_w(1);
  load_w(2); write_w(2);
  load_w(3); write_w(3);
  if (producer) write_x(0);            // loads long since landed
  wg_barrier();

  // ---- main loop: 16 epochs, roles fully decoupled ----------------------
  for (int ch = 0; ch < NEP; ++ch) {
    if (producer) {
      if (ch < NEP - 1) {
        load_x(ch + 1);                // global latency overlaps consumer MFMA
        write_x((ch + 1) & 1);         // counted vmcnt on xr only
      }
    } else {
      f32x4 acc[2][4] = {};
      const short* xbuf = Xs[ch & 1];
      #pragma unroll
      for (int ks = 0; ks < 8; ++ks) { // full K = 8 slices of 32
        const int kb = ks * 32 + lk * 8;
        bf16x8 a[2], b[4];
        #pragma unroll
        for (int fm = 0; fm < 2; ++fm)
          a[fm] = *reinterpret_cast<const bf16x8*>(
              &xbuf[xsw(fm * 16 + lrow, kb)]);
        #pragma unroll
        for (int fn = 0; fn < 4; ++fn)
          b[fn] = *reinterpret_cast<const bf16x8*>(
              &Ws[wsw(q * 64 + fn * 16 + lrow, kb)]);
        #pragma unroll
        for (int fm = 0; fm < 2; ++fm)
          #pragma unroll
          for (int fn = 0; fn < 4; ++fn)
            acc[fm][fn] = __builtin_amdgcn_mfma_f32_16x16x32_bf16(
                a[fm], b[fn], acc[fm][fn], 0, 0, 0);
      }
      // epilogue: bias + plain f32 stores (fire and forget)
      #pragma unroll
      for (int fm = 0; fm < 2; ++fm) {
        const int r0w = ch * CHM + fm * 16 + lk * 4;
        #pragma unroll
        for (int fn = 0; fn < 4; ++fn) {
          const int col = q * 64 + fn * 16 + lrow;
          float* op = ob + (size_t)r0w * DOUT + col;
          #pragma unroll
          for (int rr = 0; rr < 4; ++rr)
            op[(size_t)rr * DOUT] = acc[fm][fn][rr] + bv[fn];
        }
      }
    }
    if (ch < NEP - 1) wg_barrier();    // publish buffer swap
  }
}

extern "C" void kernel_launch(void* const* d_in, const int* in_sizes, int n_in,
                              void* d_out, int out_size, void* d_ws, size_t ws_size,
                              hipStream_t stream) {
  const float* x    = (const float*)d_in[0];
  const int*   idx  = (const int*)d_in[1];
  const float* w    = (const float*)d_in[2];
  const float* bias = (const float*)d_in[3];
  float* out = (float*)d_out;

  adaptive_linear_v8<<<NT, 512, 0, stream>>>(x, idx, w, bias, out);
}